// Round 3
// baseline (296.493 us; speedup 1.0000x reference)
//
#include <hip/hip_runtime.h>

#define TT 4096          // signal length
#define NN 8192          // padded length
#define NF 4096          // FFT length = 16^3

// XOR swizzle: permutes low 4 bits by a hash of the row; measured ~2% LDS
// bank-conflict overhead in R4 across all access patterns used here.
#define SW(i) ((i) ^ ((((i) >> 4) ^ ((i) >> 8)) & 15))

// hardware sin/cos of 2*pi*x (x in revolutions); args here are exact dyadics
__device__ __forceinline__ float sin2pi(float x) { return __builtin_amdgcn_sinf(x); }
__device__ __forceinline__ float cos2pi(float x) { return __builtin_amdgcn_cosf(x); }

// (ar,ai) *= (br,bi)
#define WMUL(ar, ai, br, bi) { float _t = (ar)*(br) - (ai)*(bi); \
                               (ai) = (ar)*(bi) + (ai)*(br); (ar) = _t; }

// e^{i*2*pi/32} — step for k -> k+256 at N=8192
#define C32 0.9807852804032304f
#define S32 0.19509032201612825f

// -------------------- register DFT16 (two radix-4 layers, DIT) --------------
// S = -1: forward (e^{-i}), S = +1: inverse (e^{+i}).
template<int S>
__device__ __forceinline__ void dft4(float& ar, float& ai, float& br, float& bi,
                                     float& cr, float& ci, float& er, float& ei) {
    float t0r = ar + cr, t0i = ai + ci;
    float t1r = ar - cr, t1i = ai - ci;
    float t2r = br + er, t2i = bi + ei;
    float t3r = br - er, t3i = bi - ei;
    ar = t0r + t2r; ai = t0i + t2i;
    cr = t0r - t2r; ci = t0i - t2i;
    br = t1r - S * t3i; bi = t1i + S * t3r;
    er = t1r + S * t3i; ei = t1i - S * t3r;
}

#define DFT16_TMULS(S, xr, xi) { \
    const float C1 = 0.9238795325112867f; \
    const float S1 = 0.3826834323650898f; \
    const float R2 = 0.7071067811865476f; \
    { float _r = xr[5]*(C1) - xi[5]*(S*S1);  xi[5]  = xr[5]*(S*S1)  + xi[5]*(C1);  xr[5]  = _r; } \
    { float _r = xr[9]*(R2) - xi[9]*(S*R2);  xi[9]  = xr[9]*(S*R2)  + xi[9]*(R2);  xr[9]  = _r; } \
    { float _r = xr[13]*(S1) - xi[13]*(S*C1); xi[13] = xr[13]*(S*C1) + xi[13]*(S1); xr[13] = _r; } \
    { float _r = xr[6]*(R2) - xi[6]*(S*R2);  xi[6]  = xr[6]*(S*R2)  + xi[6]*(R2);  xr[6]  = _r; } \
    { float _r = -S * xi[10]; xi[10] = S * xr[10]; xr[10] = _r; } \
    { float _r = xr[14]*(-R2) - xi[14]*(S*R2); xi[14] = xr[14]*(S*R2) + xi[14]*(-R2); xr[14] = _r; } \
    { float _r = xr[7]*(S1) - xi[7]*(S*C1);  xi[7]  = xr[7]*(S*C1)  + xi[7]*(S1);  xr[7]  = _r; } \
    { float _r = xr[11]*(-R2) - xi[11]*(S*R2); xi[11] = xr[11]*(S*R2) + xi[11]*(-R2); xr[11] = _r; } \
    { float _r = xr[15]*(-C1) - xi[15]*(-S*S1); xi[15] = xr[15]*(-S*S1) + xi[15]*(-C1); xr[15] = _r; } }

template<int S>
__device__ __forceinline__ void dft16(float xr[16], float xi[16]) {
    #pragma unroll
    for (int n0 = 0; n0 < 4; ++n0)
        dft4<S>(xr[n0], xi[n0], xr[n0 + 4], xi[n0 + 4],
                xr[n0 + 8], xi[n0 + 8], xr[n0 + 12], xi[n0 + 12]);

    DFT16_TMULS(S, xr, xi)

    #pragma unroll
    for (int k0 = 0; k0 < 4; ++k0)
        dft4<S>(xr[4*k0], xi[4*k0], xr[4*k0+1], xi[4*k0+1],
                xr[4*k0+2], xi[4*k0+2], xr[4*k0+3], xi[4*k0+3]);

    float tr[16], ti[16];
    #pragma unroll
    for (int q = 0; q < 16; ++q) { int p = 4*(q & 3) + (q >> 2); tr[q] = xr[p]; ti[q] = xi[p]; }
    #pragma unroll
    for (int q = 0; q < 16; ++q) { xr[q] = tr[q]; xi[q] = ti[q]; }
}

// Post-DFT twiddle: x[q] *= w^q with w given by (w1r,w1i); exact reset to
// w^8 = (w8r,w8i) at the midpoint caps the recurrence chain at 7 muls.
__device__ __forceinline__ void twiddle16(float xr[16], float xi[16],
                                          float w1r, float w1i,
                                          float w8r, float w8i) {
    float wr = w1r, wi = w1i;
    #pragma unroll
    for (int q = 1; q < 16; ++q) {
        float _r = xr[q]*wr - xi[q]*wi;
        xi[q] = xr[q]*wi + xi[q]*wr; xr[q] = _r;
        if (q == 7) { wr = w8r; wi = w8i; }
        else        { WMUL(wr, wi, w1r, w1i) }
    }
}

// Pruned final-stage DFT16: only natural outputs q in [4,12) are ever needed.
// Output transpose p = 4*(q&3)+(q>>2) means we need only the "b" (q=4+k0) and
// "c" (q=8+k0) outputs of each second-layer dft4.
// y[i2] corresponds to natural output q = 4+i2 (i2 in [0,8)).
template<int S>
__device__ __forceinline__ void dft16_mid8(float xr[16], float xi[16],
                                           float yr[8], float yi[8]) {
    #pragma unroll
    for (int n0 = 0; n0 < 4; ++n0)
        dft4<S>(xr[n0], xi[n0], xr[n0 + 4], xi[n0 + 4],
                xr[n0 + 8], xi[n0 + 8], xr[n0 + 12], xi[n0 + 12]);

    DFT16_TMULS(S, xr, xi)

    #pragma unroll
    for (int k0 = 0; k0 < 4; ++k0) {
        float ar = xr[4*k0],     ai = xi[4*k0];
        float br = xr[4*k0 + 1], bi = xi[4*k0 + 1];
        float cr = xr[4*k0 + 2], ci = xi[4*k0 + 2];
        float er = xr[4*k0 + 3], ei = xi[4*k0 + 3];
        float t0r = ar + cr, t0i = ai + ci;
        float t1r = ar - cr, t1i = ai - ci;
        float t2r = br + er, t2i = bi + ei;
        float t3r = br - er, t3i = bi - ei;
        yr[k0]     = t1r - S * t3i;  yi[k0]     = t1i + S * t3r;  // natural q = 4+k0
        yr[4 + k0] = t0r - t2r;      yi[4 + k0] = t0i - t2i;      // natural q = 8+k0
    }
}

__device__ __forceinline__ int refl(int p) {
    if (p < 2048) return 2047 - p;
    if (p < 6144) return p - 2048;
    return 10239 - p;
}

// -------------------- forward: real-8192 FFT via packed complex-4096 ---------
__global__ __launch_bounds__(256) void fwd_kernel(const float* __restrict__ in,
                                                  float2* __restrict__ F) {
    __shared__ float2 lds[NF];
    const int b = blockIdx.x, tid = threadIdx.x;
    const float* row = in + b * TT;

    float xr[16], xi[16];

    // ---- staging + stage 0 (stride 256), fused in registers ----
    #pragma unroll
    for (int r = 0; r < 16; ++r) {
        const int i = tid + 256 * r;
        xr[r] = row[refl(2 * i)];
        xi[r] = row[refl(2 * i + 1)];
    }
    dft16<-1>(xr, xi);
    twiddle16(xr, xi,
              cos2pi((float)tid * (1.0f / 4096.0f)), -sin2pi((float)tid * (1.0f / 4096.0f)),
              cos2pi((float)tid * (1.0f / 512.0f)),  -sin2pi((float)tid * (1.0f / 512.0f)));
    #pragma unroll
    for (int q = 0; q < 16; ++q) lds[SW(tid + 256 * q)] = make_float2(xr[q], xi[q]);
    __syncthreads();

    // ---- stage 1 (stride 16) ----
    {
        const int j = tid & 15;
        const int base = ((tid >> 4) << 8) + j;
        #pragma unroll
        for (int q = 0; q < 16; ++q) {
            float2 v = lds[SW(base + 16 * q)];
            xr[q] = v.x; xi[q] = v.y;
        }
        dft16<-1>(xr, xi);
        twiddle16(xr, xi,
                  cos2pi((float)j * (1.0f / 256.0f)), -sin2pi((float)j * (1.0f / 256.0f)),
                  cos2pi((float)j * (1.0f / 32.0f)),  -sin2pi((float)j * (1.0f / 32.0f)));
        #pragma unroll
        for (int q = 0; q < 16; ++q) lds[SW(base + 16 * q)] = make_float2(xr[q], xi[q]);
    }
    __syncthreads();

    // ---- stage 2 (twiddle-free) + natural-order scatter ----
    {
        const int base = tid << 4;
        const int f2 = (tid ^ (tid >> 4)) & 15;
        #pragma unroll
        for (int q = 0; q < 16; ++q) {
            float2 v = lds[base + (q ^ f2)];
            xr[q] = v.x; xi[q] = v.y;
        }
        dft16<-1>(xr, xi);
        __syncthreads();
        const int c = tid & 15;
        const int h = tid >> 4;
        #pragma unroll
        for (int q = 0; q < 16; ++q)
            lds[(q << 8) + (c << 4) + (h ^ c ^ q)] = make_float2(xr[q], xi[q]);
    }
    __syncthreads();

    // ---- epilogue: unpack real FFT; twiddle (c,s) by recurrence over r ----
    {
        const float c0 = cos2pi((float)(tid + 1) * (1.0f / 8192.0f));
        const float s0 = sin2pi((float)(tid + 1) * (1.0f / 8192.0f));
        float cc = c0, ss = s0;
        #pragma unroll
        for (int r = 0; r < 16; ++r) {
            const int i = tid + 256 * r;
            const int k = i + 1;
            const float2 za = lds[SW(k & (NF - 1))];
            const float2 zb = lds[SW((NF - k) & (NF - 1))];
            const float fer = 0.5f * (za.x + zb.x), fei = 0.5f * (za.y - zb.y);
            const float fo_r = 0.5f * (za.y + zb.y), fo_i = -0.5f * (za.x - zb.x);
            F[b * NF + i] = make_float2(fer + cc * fo_r + ss * fo_i,
                                        fei + cc * fo_i - ss * fo_r);
            if (r == 7) { cc = -s0; ss = c0; }        // exact: * e^{i*pi/2}
            else        { WMUL(cc, ss, C32, S32) }
        }
    }
}

// -------------------- inverse: one block per (batch, scale) ------------------
// d_k = F[b,k]*wft[j,k+1]; half-band 8192-IFFT = two 4096-IFFTs (signal0 =
// even samples, signal1 = odd).  R3: the two signals now TIME-MULTIPLEX one
// 32 KB float2 LDS buffer (was one 64 KB float4 buffer) -> 4 blocks/CU
// instead of 2.  7 barriers instead of 2, but each inter-barrier region
// overlaps the other signal's butterfly/twiddle compute, and 4 resident
// blocks cover barrier drains.  Per-signal arithmetic is bitwise identical
// to R2.  Stage 2 stays fused with the epilogue (nibble-swapped ownership:
// thread t's 8 pruned outputs are exactly natural n = (4+i2)*256 + t).
__global__ __launch_bounds__(256, 4) void inv_kernel(const float2* __restrict__ F,
                                                     const float* __restrict__ wft,
                                                     float* __restrict__ out,
                                                     int NS) {
    __shared__ float2 lds2[NF];                // 32 KB
    const int blk = blockIdx.x;
    const int b = blk / NS;
    const int j = blk - b * NS;
    const int tid = threadIdx.x;

    const float2* Frow = F + b * NF;
    const float* wrow = wft + (size_t)j * NN + 1;
    float* orow = out + (size_t)(b * NS + j) * TT;
    const float LOGN = 9.0109131020007136f;       // log(8192)
    const float HALF_LN2 = 0.34657359027997264f;  // 0.5 * ln(2)

    float xr0[16], xi0[16], xr1[16], xi1[16];

    // ---- staging + stage 0 (stride 256), fused in registers ----
    // d0 = F*w ; d1 = d0 * e^{+2*pi*i*k/8192}, k = tid + 256*r.
    // Global loads grouped 8-at-a-time for MLP; twiddle advances by exact
    // e^{i*2pi/32} per r with exact e^{i*pi/2} reset at r=8.
    {
        const float c0 = cos2pi((float)tid * (1.0f / 8192.0f));
        const float s0 = sin2pi((float)tid * (1.0f / 8192.0f));
        float cr = c0, ci = s0;
        #pragma unroll
        for (int g = 0; g < 2; ++g) {
            float2 fb[8]; float wb[8];
            #pragma unroll
            for (int t2 = 0; t2 < 8; ++t2) {
                const int k = tid + 256 * (8 * g + t2);
                fb[t2] = Frow[k];
                wb[t2] = wrow[k];
            }
            #pragma unroll
            for (int t2 = 0; t2 < 8; ++t2) {
                const int r = 8 * g + t2;
                const float d0r = fb[t2].x * wb[t2], d0i = fb[t2].y * wb[t2];
                xr0[r] = d0r; xi0[r] = d0i;
                xr1[r] = d0r * cr - d0i * ci;
                xi1[r] = d0r * ci + d0i * cr;
                if (r == 7) { cr = -s0; ci = c0; }
                else        { WMUL(cr, ci, C32, S32) }
            }
        }
    }
    dft16<1>(xr0, xi0);
    dft16<1>(xr1, xi1);

    const float t0w1r = cos2pi((float)tid * (1.0f / 4096.0f));
    const float t0w1i = sin2pi((float)tid * (1.0f / 4096.0f));
    const float t0w8r = cos2pi((float)tid * (1.0f / 512.0f));
    const float t0w8i = sin2pi((float)tid * (1.0f / 512.0f));
    twiddle16(xr0, xi0, t0w1r, t0w1i, t0w8r, t0w8i);

    // ================= boundary A (stage0 -> stage1 transpose) ==============
    #pragma unroll
    for (int q = 0; q < 16; ++q)
        lds2[SW(tid + 256 * q)] = make_float2(xr0[q], xi0[q]);
    __syncthreads();                                           // A1: s0 written

    const int jj = tid & 15;
    const int base1 = ((tid >> 4) << 8) + jj;
    #pragma unroll
    for (int q = 0; q < 16; ++q) {
        float2 v = lds2[SW(base1 + 16 * q)];
        xr0[q] = v.x; xi0[q] = v.y;
    }
    twiddle16(xr1, xi1, t0w1r, t0w1i, t0w8r, t0w8i);           // overlap: s1 stage-0 twiddle
    __syncthreads();                                           // A2: s0 reads done

    #pragma unroll
    for (int q = 0; q < 16; ++q)
        lds2[SW(tid + 256 * q)] = make_float2(xr1[q], xi1[q]);
    dft16<1>(xr0, xi0);                                        // overlap: s0 stage-1 butterfly
    const float w1r = cos2pi((float)jj * (1.0f / 256.0f));
    const float w1i = sin2pi((float)jj * (1.0f / 256.0f));
    const float w8r = cos2pi((float)jj * (1.0f / 32.0f));
    const float w8i = sin2pi((float)jj * (1.0f / 32.0f));
    twiddle16(xr0, xi0, w1r, w1i, w8r, w8i);
    __syncthreads();                                           // A3: s1 written

    #pragma unroll
    for (int q = 0; q < 16; ++q) {
        float2 v = lds2[SW(base1 + 16 * q)];
        xr1[q] = v.x; xi1[q] = v.y;
    }
    __syncthreads();                                           // A4: s1 reads done

    // ================= boundary B (stage1 -> stage2 transpose) ==============
    #pragma unroll
    for (int q = 0; q < 16; ++q)
        lds2[SW(base1 + 16 * q)] = make_float2(xr0[q], xi0[q]);
    dft16<1>(xr1, xi1);                                        // overlap: s1 stage-1 butterfly
    twiddle16(xr1, xi1, w1r, w1i, w8r, w8i);
    __syncthreads();                                           // B1: s0 written

    // Stage-2 fused gather: thread t owns former-thread ns = nibbleswap(t);
    // its 8 pruned outputs are natural n = (4+i2)*256 + t (store direct).
    const int ns = ((tid & 15) << 4) | (tid >> 4);
    const int base2 = ns << 4;
    const int f2 = (ns ^ (ns >> 4)) & 15;
    #pragma unroll
    for (int q = 0; q < 16; ++q) {
        float2 v = lds2[base2 + (q ^ f2)];                     // == lds2[SW(base2+q)]
        xr0[q] = v.x; xi0[q] = v.y;
    }
    __syncthreads();                                           // B2: s0 reads done

    #pragma unroll
    for (int q = 0; q < 16; ++q)
        lds2[SW(base1 + 16 * q)] = make_float2(xr1[q], xi1[q]);
    float yv0[8];
    {
        float yr0[8], yi0[8];
        dft16_mid8<1>(xr0, xi0, yr0, yi0);                     // overlap: s0 stage-2 + logs
        #pragma unroll
        for (int i2 = 0; i2 < 8; ++i2) {
            const float m0 = yr0[i2] * yr0[i2] + yi0[i2] * yi0[i2];
            yv0[i2] = HALF_LN2 * __builtin_amdgcn_logf(m0) - LOGN;
        }
    }
    __syncthreads();                                           // B3: s1 written

    #pragma unroll
    for (int q = 0; q < 16; ++q) {
        float2 v = lds2[base2 + (q ^ f2)];
        xr1[q] = v.x; xi1[q] = v.y;
    }
    {
        float yr1[8], yi1[8];
        dft16_mid8<1>(xr1, xi1, yr1, yi1);
        #pragma unroll
        for (int i2 = 0; i2 < 8; ++i2) {
            const float m1 = yr1[i2] * yr1[i2] + yi1[i2] * yi1[i2];
            const float v1 = HALF_LN2 * __builtin_amdgcn_logf(m1) - LOGN;
            ((float2*)orow)[tid + 256 * i2] = make_float2(yv0[i2], v1);
        }
    }
}

extern "C" void kernel_launch(void* const* d_in, const int* in_sizes, int n_in,
                              void* d_out, int out_size, void* d_ws, size_t ws_size,
                              hipStream_t stream) {
    const float* inputs = (const float*)d_in[0];
    const float* wft = (const float*)d_in[1];
    float* out = (float*)d_out;

    const int B = in_sizes[0] / TT;     // 64
    const int NS = in_sizes[1] / NN;    // 75

    float2* F = (float2*)d_ws;          // B*4096 complex = 2 MB

    hipLaunchKernelGGL(fwd_kernel, dim3(B), dim3(256), 0, stream, inputs, F);
    hipLaunchKernelGGL(inv_kernel, dim3(B * NS), dim3(256), 0, stream, F, wft, out, NS);
}

// Round 4
// 186.648 us; speedup vs baseline: 1.5885x; 1.5885x over previous
//
#include <hip/hip_runtime.h>

#define TT 4096          // signal length
#define NN 8192          // padded length
#define NF 4096          // FFT length = 16^3

// XOR swizzle: permutes low 4 bits by a hash of the row; measured ~2% LDS
// bank-conflict overhead in R4 across all access patterns used here.
#define SW(i) ((i) ^ ((((i) >> 4) ^ ((i) >> 8)) & 15))

// hardware sin/cos of 2*pi*x (x in revolutions); args here are exact dyadics
__device__ __forceinline__ float sin2pi(float x) { return __builtin_amdgcn_sinf(x); }
__device__ __forceinline__ float cos2pi(float x) { return __builtin_amdgcn_cosf(x); }

// (ar,ai) *= (br,bi)
#define WMUL(ar, ai, br, bi) { float _t = (ar)*(br) - (ai)*(bi); \
                               (ai) = (ar)*(bi) + (ai)*(br); (ar) = _t; }

// e^{i*2*pi/32} — step for k -> k+256 at N=8192
#define C32 0.9807852804032304f
#define S32 0.19509032201612825f

// -------------------- register DFT16 (two radix-4 layers, DIT) --------------
// S = -1: forward (e^{-i}), S = +1: inverse (e^{+i}).
template<int S>
__device__ __forceinline__ void dft4(float& ar, float& ai, float& br, float& bi,
                                     float& cr, float& ci, float& er, float& ei) {
    float t0r = ar + cr, t0i = ai + ci;
    float t1r = ar - cr, t1i = ai - ci;
    float t2r = br + er, t2i = bi + ei;
    float t3r = br - er, t3i = bi - ei;
    ar = t0r + t2r; ai = t0i + t2i;
    cr = t0r - t2r; ci = t0i - t2i;
    br = t1r - S * t3i; bi = t1i + S * t3r;
    er = t1r + S * t3i; ei = t1i - S * t3r;
}

#define DFT16_TMULS(S, xr, xi) { \
    const float C1 = 0.9238795325112867f; \
    const float S1 = 0.3826834323650898f; \
    const float R2 = 0.7071067811865476f; \
    { float _r = xr[5]*(C1) - xi[5]*(S*S1);  xi[5]  = xr[5]*(S*S1)  + xi[5]*(C1);  xr[5]  = _r; } \
    { float _r = xr[9]*(R2) - xi[9]*(S*R2);  xi[9]  = xr[9]*(S*R2)  + xi[9]*(R2);  xr[9]  = _r; } \
    { float _r = xr[13]*(S1) - xi[13]*(S*C1); xi[13] = xr[13]*(S*C1) + xi[13]*(S1); xr[13] = _r; } \
    { float _r = xr[6]*(R2) - xi[6]*(S*R2);  xi[6]  = xr[6]*(S*R2)  + xi[6]*(R2);  xr[6]  = _r; } \
    { float _r = -S * xi[10]; xi[10] = S * xr[10]; xr[10] = _r; } \
    { float _r = xr[14]*(-R2) - xi[14]*(S*R2); xi[14] = xr[14]*(S*R2) + xi[14]*(-R2); xr[14] = _r; } \
    { float _r = xr[7]*(S1) - xi[7]*(S*C1);  xi[7]  = xr[7]*(S*C1)  + xi[7]*(S1);  xr[7]  = _r; } \
    { float _r = xr[11]*(-R2) - xi[11]*(S*R2); xi[11] = xr[11]*(S*R2) + xi[11]*(-R2); xr[11] = _r; } \
    { float _r = xr[15]*(-C1) - xi[15]*(-S*S1); xi[15] = xr[15]*(-S*S1) + xi[15]*(-C1); xr[15] = _r; } }

template<int S>
__device__ __forceinline__ void dft16(float xr[16], float xi[16]) {
    #pragma unroll
    for (int n0 = 0; n0 < 4; ++n0)
        dft4<S>(xr[n0], xi[n0], xr[n0 + 4], xi[n0 + 4],
                xr[n0 + 8], xi[n0 + 8], xr[n0 + 12], xi[n0 + 12]);

    DFT16_TMULS(S, xr, xi)

    #pragma unroll
    for (int k0 = 0; k0 < 4; ++k0)
        dft4<S>(xr[4*k0], xi[4*k0], xr[4*k0+1], xi[4*k0+1],
                xr[4*k0+2], xi[4*k0+2], xr[4*k0+3], xi[4*k0+3]);

    float tr[16], ti[16];
    #pragma unroll
    for (int q = 0; q < 16; ++q) { int p = 4*(q & 3) + (q >> 2); tr[q] = xr[p]; ti[q] = xi[p]; }
    #pragma unroll
    for (int q = 0; q < 16; ++q) { xr[q] = tr[q]; xi[q] = ti[q]; }
}

// Post-DFT twiddle: x[q] *= w^q with w given by (w1r,w1i); exact reset to
// w^8 = (w8r,w8i) at the midpoint caps the recurrence chain at 7 muls.
__device__ __forceinline__ void twiddle16(float xr[16], float xi[16],
                                          float w1r, float w1i,
                                          float w8r, float w8i) {
    float wr = w1r, wi = w1i;
    #pragma unroll
    for (int q = 1; q < 16; ++q) {
        float _r = xr[q]*wr - xi[q]*wi;
        xi[q] = xr[q]*wi + xi[q]*wr; xr[q] = _r;
        if (q == 7) { wr = w8r; wi = w8i; }
        else        { WMUL(wr, wi, w1r, w1i) }
    }
}

// Pruned final-stage DFT16: only natural outputs q in [4,12) are ever needed.
// Output transpose p = 4*(q&3)+(q>>2) means we need only the "b" (q=4+k0) and
// "c" (q=8+k0) outputs of each second-layer dft4.
// y[i2] corresponds to natural output q = 4+i2 (i2 in [0,8)).
template<int S>
__device__ __forceinline__ void dft16_mid8(float xr[16], float xi[16],
                                           float yr[8], float yi[8]) {
    #pragma unroll
    for (int n0 = 0; n0 < 4; ++n0)
        dft4<S>(xr[n0], xi[n0], xr[n0 + 4], xi[n0 + 4],
                xr[n0 + 8], xi[n0 + 8], xr[n0 + 12], xi[n0 + 12]);

    DFT16_TMULS(S, xr, xi)

    #pragma unroll
    for (int k0 = 0; k0 < 4; ++k0) {
        float ar = xr[4*k0],     ai = xi[4*k0];
        float br = xr[4*k0 + 1], bi = xi[4*k0 + 1];
        float cr = xr[4*k0 + 2], ci = xi[4*k0 + 2];
        float er = xr[4*k0 + 3], ei = xi[4*k0 + 3];
        float t0r = ar + cr, t0i = ai + ci;
        float t1r = ar - cr, t1i = ai - ci;
        float t2r = br + er, t2i = bi + ei;
        float t3r = br - er, t3i = bi - ei;
        yr[k0]     = t1r - S * t3i;  yi[k0]     = t1i + S * t3r;  // natural q = 4+k0
        yr[4 + k0] = t0r - t2r;      yi[4 + k0] = t0i - t2i;      // natural q = 8+k0
    }
}

__device__ __forceinline__ int refl(int p) {
    if (p < 2048) return 2047 - p;
    if (p < 6144) return p - 2048;
    return 10239 - p;
}

// -------------------- forward: real-8192 FFT via packed complex-4096 ---------
__global__ __launch_bounds__(256) void fwd_kernel(const float* __restrict__ in,
                                                  float2* __restrict__ F) {
    __shared__ float2 lds[NF];
    const int b = blockIdx.x, tid = threadIdx.x;
    const float* row = in + b * TT;

    float xr[16], xi[16];

    // ---- staging + stage 0 (stride 256), fused in registers ----
    #pragma unroll
    for (int r = 0; r < 16; ++r) {
        const int i = tid + 256 * r;
        xr[r] = row[refl(2 * i)];
        xi[r] = row[refl(2 * i + 1)];
    }
    dft16<-1>(xr, xi);
    twiddle16(xr, xi,
              cos2pi((float)tid * (1.0f / 4096.0f)), -sin2pi((float)tid * (1.0f / 4096.0f)),
              cos2pi((float)tid * (1.0f / 512.0f)),  -sin2pi((float)tid * (1.0f / 512.0f)));
    #pragma unroll
    for (int q = 0; q < 16; ++q) lds[SW(tid + 256 * q)] = make_float2(xr[q], xi[q]);
    __syncthreads();

    // ---- stage 1 (stride 16) ----
    {
        const int j = tid & 15;
        const int base = ((tid >> 4) << 8) + j;
        #pragma unroll
        for (int q = 0; q < 16; ++q) {
            float2 v = lds[SW(base + 16 * q)];
            xr[q] = v.x; xi[q] = v.y;
        }
        dft16<-1>(xr, xi);
        twiddle16(xr, xi,
                  cos2pi((float)j * (1.0f / 256.0f)), -sin2pi((float)j * (1.0f / 256.0f)),
                  cos2pi((float)j * (1.0f / 32.0f)),  -sin2pi((float)j * (1.0f / 32.0f)));
        #pragma unroll
        for (int q = 0; q < 16; ++q) lds[SW(base + 16 * q)] = make_float2(xr[q], xi[q]);
    }
    __syncthreads();

    // ---- stage 2 (twiddle-free) + natural-order scatter ----
    {
        const int base = tid << 4;
        const int f2 = (tid ^ (tid >> 4)) & 15;
        #pragma unroll
        for (int q = 0; q < 16; ++q) {
            float2 v = lds[base + (q ^ f2)];
            xr[q] = v.x; xi[q] = v.y;
        }
        dft16<-1>(xr, xi);
        __syncthreads();
        const int c = tid & 15;
        const int h = tid >> 4;
        #pragma unroll
        for (int q = 0; q < 16; ++q)
            lds[(q << 8) + (c << 4) + (h ^ c ^ q)] = make_float2(xr[q], xi[q]);
    }
    __syncthreads();

    // ---- epilogue: unpack real FFT; twiddle (c,s) by recurrence over r ----
    {
        const float c0 = cos2pi((float)(tid + 1) * (1.0f / 8192.0f));
        const float s0 = sin2pi((float)(tid + 1) * (1.0f / 8192.0f));
        float cc = c0, ss = s0;
        #pragma unroll
        for (int r = 0; r < 16; ++r) {
            const int i = tid + 256 * r;
            const int k = i + 1;
            const float2 za = lds[SW(k & (NF - 1))];
            const float2 zb = lds[SW((NF - k) & (NF - 1))];
            const float fer = 0.5f * (za.x + zb.x), fei = 0.5f * (za.y - zb.y);
            const float fo_r = 0.5f * (za.y + zb.y), fo_i = -0.5f * (za.x - zb.x);
            F[b * NF + i] = make_float2(fer + cc * fo_r + ss * fo_i,
                                        fei + cc * fo_i - ss * fo_r);
            if (r == 7) { cc = -s0; ss = c0; }        // exact: * e^{i*pi/2}
            else        { WMUL(cc, ss, C32, S32) }
        }
    }
}

// -------------------- inverse: one block per (batch, scale) ------------------
// d_k = F[b,k]*wft[j,k+1]; half-band 8192-IFFT = two 4096-IFFTs (signal0 =
// even samples, signal1 = odd).  R4: SPLIT BY SIGNAL — 512 threads/block,
// group sig = threadIdx.x>>8 runs the full R2 single-signal radix-16 pipeline
// on its own 32 KB float2 LDS buffer.  Per-thread live state halves (32
// floats) -> VGPR ~70, no spill (R3's failure was a 64-VGPR cap + 128 floats
// of state -> 370 MB scratch fetch).  64 KB LDS -> 2 blocks/CU = 16 waves/CU
// (~50% occ vs R2's 20%).  Same arithmetic per signal as R2, same 2 barriers.
// Stage 2 stays fused with the epilogue (nibble-swapped ownership: thread t's
// 8 pruned outputs are exactly natural n = (4+i2)*256 + t); the two groups'
// interleaved scalar stores (orow[2p+sig]) merge in write-back L2.
__global__ __launch_bounds__(512) void inv_kernel(const float2* __restrict__ F,
                                                  const float* __restrict__ wft,
                                                  float* __restrict__ out,
                                                  int NS) {
    __shared__ float2 ldsb[2][NF];             // 64 KB total
    const int blk = blockIdx.x;
    const int b = blk / NS;
    const int j = blk - b * NS;
    const int tid = (int)threadIdx.x & 255;
    const int sig = (int)threadIdx.x >> 8;
    float2* lds = ldsb[sig];

    const float2* Frow = F + b * NF;
    const float* wrow = wft + (size_t)j * NN + 1;
    float* orow = out + (size_t)(b * NS + j) * TT;
    const float LOGN = 9.0109131020007136f;       // log(8192)
    const float HALF_LN2 = 0.34657359027997264f;  // 0.5 * ln(2)

    float xr[16], xi[16];

    // ---- staging + stage 0 (stride 256), fused in registers ----
    // d = F*w ; signal 1 additionally rotates by e^{+2*pi*i*k/8192}.
    // Phase advances by exact e^{i*2pi/32} per r, exact e^{i*pi/2} reset at r=8.
    {
        const float c0 = cos2pi((float)tid * (1.0f / 8192.0f));
        const float s0 = sin2pi((float)tid * (1.0f / 8192.0f));
        float cr = c0, ci = s0;
        #pragma unroll
        for (int g = 0; g < 2; ++g) {
            float2 fb[8]; float wb[8];
            #pragma unroll
            for (int t2 = 0; t2 < 8; ++t2) {
                const int k = tid + 256 * (8 * g + t2);
                fb[t2] = Frow[k];
                wb[t2] = wrow[k];
            }
            #pragma unroll
            for (int t2 = 0; t2 < 8; ++t2) {
                const int r = 8 * g + t2;
                float dr = fb[t2].x * wb[t2], di = fb[t2].y * wb[t2];
                if (sig) {                        // wave-uniform branch
                    float _t = dr * cr - di * ci;
                    di = dr * ci + di * cr;
                    dr = _t;
                }
                if (r == 7) { cr = -s0; ci = c0; }
                else        { WMUL(cr, ci, C32, S32) }
                xr[r] = dr; xi[r] = di;
            }
        }
    }
    dft16<1>(xr, xi);
    twiddle16(xr, xi,
              cos2pi((float)tid * (1.0f / 4096.0f)), sin2pi((float)tid * (1.0f / 4096.0f)),
              cos2pi((float)tid * (1.0f / 512.0f)),  sin2pi((float)tid * (1.0f / 512.0f)));
    #pragma unroll
    for (int q = 0; q < 16; ++q)
        lds[SW(tid + 256 * q)] = make_float2(xr[q], xi[q]);
    __syncthreads();

    // ---- stage 1: stride 16, j = tid&15 ----
    {
        const int jj = tid & 15;
        const int base = ((tid >> 4) << 8) + jj;
        #pragma unroll
        for (int q = 0; q < 16; ++q) {
            float2 v = lds[SW(base + 16 * q)];
            xr[q] = v.x; xi[q] = v.y;
        }
        dft16<1>(xr, xi);
        twiddle16(xr, xi,
                  cos2pi((float)jj * (1.0f / 256.0f)), sin2pi((float)jj * (1.0f / 256.0f)),
                  cos2pi((float)jj * (1.0f / 32.0f)),  sin2pi((float)jj * (1.0f / 32.0f)));
        #pragma unroll
        for (int q = 0; q < 16; ++q)
            lds[SW(base + 16 * q)] = make_float2(xr[q], xi[q]);
    }
    __syncthreads();

    // ---- stage 2 fused with epilogue ----
    // Thread t runs the butterfly of former-thread ns = nibbleswap(t); its 8
    // pruned outputs are natural n = (4+i2)*256 + t -> time 2n+sig, store direct.
    {
        const int ns = ((tid & 15) << 4) | (tid >> 4);   // nibble-swap
        const int base = ns << 4;
        const int f2 = (ns ^ (ns >> 4)) & 15;
        #pragma unroll
        for (int q = 0; q < 16; ++q) {
            float2 v = lds[base + (q ^ f2)];             // == lds[SW(base+q)]
            xr[q] = v.x; xi[q] = v.y;
        }
        float yr[8], yi[8];
        dft16_mid8<1>(xr, xi, yr, yi);
        #pragma unroll
        for (int i2 = 0; i2 < 8; ++i2) {
            const float m = yr[i2] * yr[i2] + yi[i2] * yi[i2];
            const float v = HALF_LN2 * __builtin_amdgcn_logf(m) - LOGN;
            orow[2 * (tid + 256 * i2) + sig] = v;
        }
    }
}

extern "C" void kernel_launch(void* const* d_in, const int* in_sizes, int n_in,
                              void* d_out, int out_size, void* d_ws, size_t ws_size,
                              hipStream_t stream) {
    const float* inputs = (const float*)d_in[0];
    const float* wft = (const float*)d_in[1];
    float* out = (float*)d_out;

    const int B = in_sizes[0] / TT;     // 64
    const int NS = in_sizes[1] / NN;    // 75

    float2* F = (float2*)d_ws;          // B*4096 complex = 2 MB

    hipLaunchKernelGGL(fwd_kernel, dim3(B), dim3(256), 0, stream, inputs, F);
    hipLaunchKernelGGL(inv_kernel, dim3(B * NS), dim3(512), 0, stream, F, wft, out, NS);
}

// Round 5
// 160.870 us; speedup vs baseline: 1.8431x; 1.1602x over previous
//
#include <hip/hip_runtime.h>

#define TT 4096          // signal length
#define NN 8192          // padded length
#define NF 4096          // FFT length = 16^3

// XOR swizzle: permutes low 4 bits by a hash of the row; measured ~2% LDS
// bank-conflict overhead in R4 across all access patterns used here.
#define SW(i) ((i) ^ ((((i) >> 4) ^ ((i) >> 8)) & 15))

// hardware sin/cos of 2*pi*x (x in revolutions); args here are exact dyadics
__device__ __forceinline__ float sin2pi(float x) { return __builtin_amdgcn_sinf(x); }
__device__ __forceinline__ float cos2pi(float x) { return __builtin_amdgcn_cosf(x); }

// (ar,ai) *= (br,bi)
#define WMUL(ar, ai, br, bi) { float _t = (ar)*(br) - (ai)*(bi); \
                               (ai) = (ar)*(bi) + (ai)*(br); (ar) = _t; }

// e^{i*2*pi/32} — step for k -> k+256 at N=8192
#define C32 0.9807852804032304f
#define S32 0.19509032201612825f

// -------------------- register DFT16 (two radix-4 layers, DIT) --------------
// S = -1: forward (e^{-i}), S = +1: inverse (e^{+i}).
template<int S>
__device__ __forceinline__ void dft4(float& ar, float& ai, float& br, float& bi,
                                     float& cr, float& ci, float& er, float& ei) {
    float t0r = ar + cr, t0i = ai + ci;
    float t1r = ar - cr, t1i = ai - ci;
    float t2r = br + er, t2i = bi + ei;
    float t3r = br - er, t3i = bi - ei;
    ar = t0r + t2r; ai = t0i + t2i;
    cr = t0r - t2r; ci = t0i - t2i;
    br = t1r - S * t3i; bi = t1i + S * t3r;
    er = t1r + S * t3i; ei = t1i - S * t3r;
}

#define DFT16_TMULS(S, xr, xi) { \
    const float C1 = 0.9238795325112867f; \
    const float S1 = 0.3826834323650898f; \
    const float R2 = 0.7071067811865476f; \
    { float _r = xr[5]*(C1) - xi[5]*(S*S1);  xi[5]  = xr[5]*(S*S1)  + xi[5]*(C1);  xr[5]  = _r; } \
    { float _r = xr[9]*(R2) - xi[9]*(S*R2);  xi[9]  = xr[9]*(S*R2)  + xi[9]*(R2);  xr[9]  = _r; } \
    { float _r = xr[13]*(S1) - xi[13]*(S*C1); xi[13] = xr[13]*(S*C1) + xi[13]*(S1); xr[13] = _r; } \
    { float _r = xr[6]*(R2) - xi[6]*(S*R2);  xi[6]  = xr[6]*(S*R2)  + xi[6]*(R2);  xr[6]  = _r; } \
    { float _r = -S * xi[10]; xi[10] = S * xr[10]; xr[10] = _r; } \
    { float _r = xr[14]*(-R2) - xi[14]*(S*R2); xi[14] = xr[14]*(S*R2) + xi[14]*(-R2); xr[14] = _r; } \
    { float _r = xr[7]*(S1) - xi[7]*(S*C1);  xi[7]  = xr[7]*(S*C1)  + xi[7]*(S1);  xr[7]  = _r; } \
    { float _r = xr[11]*(-R2) - xi[11]*(S*R2); xi[11] = xr[11]*(S*R2) + xi[11]*(-R2); xr[11] = _r; } \
    { float _r = xr[15]*(-C1) - xi[15]*(-S*S1); xi[15] = xr[15]*(-S*S1) + xi[15]*(-C1); xr[15] = _r; } }

template<int S>
__device__ __forceinline__ void dft16(float xr[16], float xi[16]) {
    #pragma unroll
    for (int n0 = 0; n0 < 4; ++n0)
        dft4<S>(xr[n0], xi[n0], xr[n0 + 4], xi[n0 + 4],
                xr[n0 + 8], xi[n0 + 8], xr[n0 + 12], xi[n0 + 12]);

    DFT16_TMULS(S, xr, xi)

    #pragma unroll
    for (int k0 = 0; k0 < 4; ++k0)
        dft4<S>(xr[4*k0], xi[4*k0], xr[4*k0+1], xi[4*k0+1],
                xr[4*k0+2], xi[4*k0+2], xr[4*k0+3], xi[4*k0+3]);

    float tr[16], ti[16];
    #pragma unroll
    for (int q = 0; q < 16; ++q) { int p = 4*(q & 3) + (q >> 2); tr[q] = xr[p]; ti[q] = xi[p]; }
    #pragma unroll
    for (int q = 0; q < 16; ++q) { xr[q] = tr[q]; xi[q] = ti[q]; }
}

// Post-DFT twiddle: x[q] *= w^q with w given by (w1r,w1i); exact reset to
// w^8 = (w8r,w8i) at the midpoint caps the recurrence chain at 7 muls.
__device__ __forceinline__ void twiddle16(float xr[16], float xi[16],
                                          float w1r, float w1i,
                                          float w8r, float w8i) {
    float wr = w1r, wi = w1i;
    #pragma unroll
    for (int q = 1; q < 16; ++q) {
        float _r = xr[q]*wr - xi[q]*wi;
        xi[q] = xr[q]*wi + xi[q]*wr; xr[q] = _r;
        if (q == 7) { wr = w8r; wi = w8i; }
        else        { WMUL(wr, wi, w1r, w1i) }
    }
}

// Pruned final-stage DFT16: only natural outputs q in [4,12) are ever needed.
// Output transpose p = 4*(q&3)+(q>>2) means we need only the "b" (q=4+k0) and
// "c" (q=8+k0) outputs of each second-layer dft4.
// y[i2] corresponds to natural output q = 4+i2 (i2 in [0,8)).
template<int S>
__device__ __forceinline__ void dft16_mid8(float xr[16], float xi[16],
                                           float yr[8], float yi[8]) {
    #pragma unroll
    for (int n0 = 0; n0 < 4; ++n0)
        dft4<S>(xr[n0], xi[n0], xr[n0 + 4], xi[n0 + 4],
                xr[n0 + 8], xi[n0 + 8], xr[n0 + 12], xi[n0 + 12]);

    DFT16_TMULS(S, xr, xi)

    #pragma unroll
    for (int k0 = 0; k0 < 4; ++k0) {
        float ar = xr[4*k0],     ai = xi[4*k0];
        float br = xr[4*k0 + 1], bi = xi[4*k0 + 1];
        float cr = xr[4*k0 + 2], ci = xi[4*k0 + 2];
        float er = xr[4*k0 + 3], ei = xi[4*k0 + 3];
        float t0r = ar + cr, t0i = ai + ci;
        float t1r = ar - cr, t1i = ai - ci;
        float t2r = br + er, t2i = bi + ei;
        float t3r = br - er, t3i = bi - ei;
        yr[k0]     = t1r - S * t3i;  yi[k0]     = t1i + S * t3r;  // natural q = 4+k0
        yr[4 + k0] = t0r - t2r;      yi[4 + k0] = t0i - t2i;      // natural q = 8+k0
    }
}

__device__ __forceinline__ int refl(int p) {
    if (p < 2048) return 2047 - p;
    if (p < 6144) return p - 2048;
    return 10239 - p;
}

// -------------------- forward: real-8192 FFT via packed complex-4096 ---------
__global__ __launch_bounds__(256) void fwd_kernel(const float* __restrict__ in,
                                                  float2* __restrict__ F) {
    __shared__ float2 lds[NF];
    const int b = blockIdx.x, tid = threadIdx.x;
    const float* row = in + b * TT;

    float xr[16], xi[16];

    // ---- staging + stage 0 (stride 256), fused in registers ----
    #pragma unroll
    for (int r = 0; r < 16; ++r) {
        const int i = tid + 256 * r;
        xr[r] = row[refl(2 * i)];
        xi[r] = row[refl(2 * i + 1)];
    }
    dft16<-1>(xr, xi);
    twiddle16(xr, xi,
              cos2pi((float)tid * (1.0f / 4096.0f)), -sin2pi((float)tid * (1.0f / 4096.0f)),
              cos2pi((float)tid * (1.0f / 512.0f)),  -sin2pi((float)tid * (1.0f / 512.0f)));
    #pragma unroll
    for (int q = 0; q < 16; ++q) lds[SW(tid + 256 * q)] = make_float2(xr[q], xi[q]);
    __syncthreads();

    // ---- stage 1 (stride 16) ----
    {
        const int j = tid & 15;
        const int base = ((tid >> 4) << 8) + j;
        #pragma unroll
        for (int q = 0; q < 16; ++q) {
            float2 v = lds[SW(base + 16 * q)];
            xr[q] = v.x; xi[q] = v.y;
        }
        dft16<-1>(xr, xi);
        twiddle16(xr, xi,
                  cos2pi((float)j * (1.0f / 256.0f)), -sin2pi((float)j * (1.0f / 256.0f)),
                  cos2pi((float)j * (1.0f / 32.0f)),  -sin2pi((float)j * (1.0f / 32.0f)));
        #pragma unroll
        for (int q = 0; q < 16; ++q) lds[SW(base + 16 * q)] = make_float2(xr[q], xi[q]);
    }
    __syncthreads();

    // ---- stage 2 (twiddle-free) + natural-order scatter ----
    {
        const int base = tid << 4;
        const int f2 = (tid ^ (tid >> 4)) & 15;
        #pragma unroll
        for (int q = 0; q < 16; ++q) {
            float2 v = lds[base + (q ^ f2)];
            xr[q] = v.x; xi[q] = v.y;
        }
        dft16<-1>(xr, xi);
        __syncthreads();
        const int c = tid & 15;
        const int h = tid >> 4;
        #pragma unroll
        for (int q = 0; q < 16; ++q)
            lds[(q << 8) + (c << 4) + (h ^ c ^ q)] = make_float2(xr[q], xi[q]);
    }
    __syncthreads();

    // ---- epilogue: unpack real FFT; twiddle (c,s) by recurrence over r ----
    {
        const float c0 = cos2pi((float)(tid + 1) * (1.0f / 8192.0f));
        const float s0 = sin2pi((float)(tid + 1) * (1.0f / 8192.0f));
        float cc = c0, ss = s0;
        #pragma unroll
        for (int r = 0; r < 16; ++r) {
            const int i = tid + 256 * r;
            const int k = i + 1;
            const float2 za = lds[SW(k & (NF - 1))];
            const float2 zb = lds[SW((NF - k) & (NF - 1))];
            const float fer = 0.5f * (za.x + zb.x), fei = 0.5f * (za.y - zb.y);
            const float fo_r = 0.5f * (za.y + zb.y), fo_i = -0.5f * (za.x - zb.x);
            F[b * NF + i] = make_float2(fer + cc * fo_r + ss * fo_i,
                                        fei + cc * fo_i - ss * fo_r);
            if (r == 7) { cc = -s0; ss = c0; }        // exact: * e^{i*pi/2}
            else        { WMUL(cc, ss, C32, S32) }
        }
    }
}

// -------------------- inverse: one block per (batch, scale, signal) ----------
// d_k = F[b,k]*wft[j,k+1]; half-band 8192-IFFT = two 4096-IFFTs (signal0 =
// even samples, signal1 = odd).  R5: ONE SIGNAL PER BLOCK — 256 threads,
// 32 KB LDS, grid = 2*B*NS.  Combines R4's low per-thread state (32 floats,
// VGPR ~76, no spill — no launch_bounds cap, R3's lesson) with R3's small-LDS
// occupancy (160/32 = 5 blocks/CU = 20 waves/CU, LDS-limited; VGPR allows 6
// waves/SIMD).  Per-signal arithmetic identical to R2/R4.  Sibling sig0/sig1
// blocks of one (b,j) are placed 8 blockIdx apart -> same XCD under %8
// round-robin and temporally adjacent, so their interleaved stride-2 stores
// merge in one L2 before writeback (R4 measured WRITE_SIZE exact, no ampl.).
__global__ __launch_bounds__(256) void inv_kernel(const float2* __restrict__ F,
                                                  const float* __restrict__ wft,
                                                  float* __restrict__ out,
                                                  int NS) {
    __shared__ float2 lds[NF];                 // 32 KB
    const int blk = blockIdx.x;
    const int nb = gridDim.x;                  // 2*B*NS (even)
    const int full = nb & ~15;
    int pairIdx, sig;
    if (blk < full) {                          // chunks of 16: 8 pairs x 2 sigs
        pairIdx = ((blk >> 4) << 3) | (blk & 7);
        sig = (blk >> 3) & 1;
    } else {                                   // even-sized tail: interleaved
        const int r = blk - full;
        pairIdx = (full >> 1) + (r >> 1);
        sig = r & 1;
    }
    const int b = pairIdx / NS;
    const int j = pairIdx - b * NS;
    const int tid = threadIdx.x;

    const float2* Frow = F + b * NF;
    const float* wrow = wft + (size_t)j * NN + 1;
    float* orow = out + (size_t)(b * NS + j) * TT;
    const float LOGN = 9.0109131020007136f;       // log(8192)
    const float HALF_LN2 = 0.34657359027997264f;  // 0.5 * ln(2)

    float xr[16], xi[16];

    // ---- staging + stage 0 (stride 256), fused in registers ----
    // d = F*w ; signal 1 additionally rotates by e^{+2*pi*i*k/8192}.
    // sig is block-uniform: sig=0 blocks skip all phase math (scalar branch).
    if (sig == 0) {
        #pragma unroll
        for (int g = 0; g < 2; ++g) {
            float2 fb[8]; float wb[8];
            #pragma unroll
            for (int t2 = 0; t2 < 8; ++t2) {
                const int k = tid + 256 * (8 * g + t2);
                fb[t2] = Frow[k];
                wb[t2] = wrow[k];
            }
            #pragma unroll
            for (int t2 = 0; t2 < 8; ++t2) {
                const int r = 8 * g + t2;
                xr[r] = fb[t2].x * wb[t2];
                xi[r] = fb[t2].y * wb[t2];
            }
        }
    } else {
        const float c0 = cos2pi((float)tid * (1.0f / 8192.0f));
        const float s0 = sin2pi((float)tid * (1.0f / 8192.0f));
        float cr = c0, ci = s0;
        #pragma unroll
        for (int g = 0; g < 2; ++g) {
            float2 fb[8]; float wb[8];
            #pragma unroll
            for (int t2 = 0; t2 < 8; ++t2) {
                const int k = tid + 256 * (8 * g + t2);
                fb[t2] = Frow[k];
                wb[t2] = wrow[k];
            }
            #pragma unroll
            for (int t2 = 0; t2 < 8; ++t2) {
                const int r = 8 * g + t2;
                const float d0r = fb[t2].x * wb[t2], d0i = fb[t2].y * wb[t2];
                xr[r] = d0r * cr - d0i * ci;
                xi[r] = d0r * ci + d0i * cr;
                if (r == 7) { cr = -s0; ci = c0; }    // exact: * e^{i*pi/2}
                else        { WMUL(cr, ci, C32, S32) }
            }
        }
    }
    dft16<1>(xr, xi);
    twiddle16(xr, xi,
              cos2pi((float)tid * (1.0f / 4096.0f)), sin2pi((float)tid * (1.0f / 4096.0f)),
              cos2pi((float)tid * (1.0f / 512.0f)),  sin2pi((float)tid * (1.0f / 512.0f)));
    #pragma unroll
    for (int q = 0; q < 16; ++q)
        lds[SW(tid + 256 * q)] = make_float2(xr[q], xi[q]);
    __syncthreads();

    // ---- stage 1: stride 16, j = tid&15 ----
    {
        const int jj = tid & 15;
        const int base = ((tid >> 4) << 8) + jj;
        #pragma unroll
        for (int q = 0; q < 16; ++q) {
            float2 v = lds[SW(base + 16 * q)];
            xr[q] = v.x; xi[q] = v.y;
        }
        dft16<1>(xr, xi);
        twiddle16(xr, xi,
                  cos2pi((float)jj * (1.0f / 256.0f)), sin2pi((float)jj * (1.0f / 256.0f)),
                  cos2pi((float)jj * (1.0f / 32.0f)),  sin2pi((float)jj * (1.0f / 32.0f)));
        #pragma unroll
        for (int q = 0; q < 16; ++q)
            lds[SW(base + 16 * q)] = make_float2(xr[q], xi[q]);
    }
    __syncthreads();

    // ---- stage 2 fused with epilogue ----
    // Thread t runs the butterfly of former-thread ns = nibbleswap(t); its 8
    // pruned outputs are natural n = (4+i2)*256 + t -> time 2n+sig, store direct.
    {
        const int ns = ((tid & 15) << 4) | (tid >> 4);   // nibble-swap
        const int base = ns << 4;
        const int f2 = (ns ^ (ns >> 4)) & 15;
        #pragma unroll
        for (int q = 0; q < 16; ++q) {
            float2 v = lds[base + (q ^ f2)];             // == lds[SW(base+q)]
            xr[q] = v.x; xi[q] = v.y;
        }
        float yr[8], yi[8];
        dft16_mid8<1>(xr, xi, yr, yi);
        #pragma unroll
        for (int i2 = 0; i2 < 8; ++i2) {
            const float m = yr[i2] * yr[i2] + yi[i2] * yi[i2];
            const float v = HALF_LN2 * __builtin_amdgcn_logf(m) - LOGN;
            orow[2 * (tid + 256 * i2) + sig] = v;
        }
    }
}

extern "C" void kernel_launch(void* const* d_in, const int* in_sizes, int n_in,
                              void* d_out, int out_size, void* d_ws, size_t ws_size,
                              hipStream_t stream) {
    const float* inputs = (const float*)d_in[0];
    const float* wft = (const float*)d_in[1];
    float* out = (float*)d_out;

    const int B = in_sizes[0] / TT;     // 64
    const int NS = in_sizes[1] / NN;    // 75

    float2* F = (float2*)d_ws;          // B*4096 complex = 2 MB

    hipLaunchKernelGGL(fwd_kernel, dim3(B), dim3(256), 0, stream, inputs, F);
    hipLaunchKernelGGL(inv_kernel, dim3(2 * B * NS), dim3(256), 0, stream, F, wft, out, NS);
}